// Round 2
// baseline (403.693 us; speedup 1.0000x reference)
//
#include <hip/hip_runtime.h>
#include <math.h>

#define BATCH 64
#define LSEQ  16384
#define DIM   64
#define KSEL  256

// ---------------------------------------------------------------------------
// Kernel 1: sims[b][l] = g * dot(q,k) / (|q||k|), computed in FP64 so the
// ordering matches the float64 numpy reference exactly (fp32 accumulation
// order differences flip ~10 adjacent top-k pairs; fp64 noise ~1e-15 rel
// vs rank-256 spacing 7e-4 rel -> swap probability ~1e-7).
// 16 lanes per key row, each lane one float4 -> 1 KB contiguous wave loads.
// ---------------------------------------------------------------------------
__global__ __launch_bounds__(256) void sim_kernel(
    const float* __restrict__ q,
    const float* __restrict__ keys,
    const float* __restrict__ gp,
    double* __restrict__ sims)
{
    const int b     = blockIdx.x >> 6;   // 64 chunks per batch
    const int chunk = blockIdx.x & 63;   // 256 rows per chunk
    const int t  = threadIdx.x;
    const int j  = t & 15;               // float4 slot within row
    const int rl = t >> 4;               // row within 16-row group

    const float4* q4 = reinterpret_cast<const float4*>(q) + b * 16;
    float4 qv = q4[j];
    const double qx = qv.x, qy = qv.y, qz = qv.z, qw = qv.w;
    double qss = qx*qx + qy*qy + qz*qz + qw*qw;
    #pragma unroll
    for (int m = 1; m < 16; m <<= 1) qss += __shfl_xor(qss, m);
    const double scale = (double)gp[0] / sqrt(qss);

    __shared__ double local[256];
    const float4* k4 = reinterpret_cast<const float4*>(keys) + (size_t)b * LSEQ * 16;
    const int row_base = chunk * 256;

    for (int it = 0; it < 16; ++it) {
        const int row = row_base + it * 16 + rl;
        float4 kv = k4[row * 16 + j];
        const double kx = kv.x, ky = kv.y, kz = kv.z, kw = kv.w;
        double dot = qx*kx + qy*ky + qz*kz + qw*kw;
        double kss = kx*kx + ky*ky + kz*kz + kw*kw;
        #pragma unroll
        for (int m = 1; m < 16; m <<= 1) {
            dot += __shfl_xor(dot, m);
            kss += __shfl_xor(kss, m);
        }
        if (j == 0) local[it * 16 + rl] = scale * dot / sqrt(kss);
    }
    __syncthreads();
    sims[(size_t)b * LSEQ + row_base + t] = local[t];   // coalesced 2 KB store
}

// ---------------------------------------------------------------------------
// Kernel 2: per-batch exact top-256 of fp64 sims (desc, ties -> lowest index),
// softmax, values gather. One block per batch.
// Radix-select on the high 32 bits of the sortable-f64 key narrows to
// <= ~260 candidates; a 512-wide bitonic sort on (full 64-bit key, ~idx)
// resolves low-bit differences and index ties exactly like jax.lax.top_k.
// ---------------------------------------------------------------------------
__global__ __launch_bounds__(256, 1) void topk_kernel(
    const double* __restrict__ sims,
    const float* __restrict__ values,
    float* __restrict__ out)
{
    const int b = blockIdx.x;
    const int t = threadIdx.x;
    const double* s = sims + (size_t)b * LSEQ;

    // Load all 16384 sims (64/thread) as monotone-sortable u64 (128 VGPRs;
    // launch_bounds(256,1) -> 512-VGPR budget, no spill).
    unsigned long long skey[64];
    #pragma unroll
    for (int it = 0; it < 64; ++it) {
        unsigned long long u =
            (unsigned long long)__double_as_longlong(s[it * 256 + t]);
        skey[it] = (u >> 63) ? ~u : (u | 0x8000000000000000ull);
    }

    __shared__ unsigned hist[256];
    __shared__ unsigned scan[256];
    __shared__ ulonglong2 cand[512];          // {sortable key, ~idx}
    __shared__ unsigned sh_prefix, sh_mask, sh_k, ccount;

    if (t == 0) { sh_prefix = 0u; sh_mask = 0u; sh_k = KSEL; ccount = 0u; }

    // Radix select on high-32 bits: 4 passes of 8 bits.
    for (int p = 0; p < 4; ++p) {
        const int shift = 24 - 8 * p;
        hist[t] = 0u;
        __syncthreads();
        const unsigned prefix = sh_prefix;
        const unsigned mask   = sh_mask;
        const unsigned kcur   = sh_k;
        #pragma unroll
        for (int it = 0; it < 64; ++it) {
            unsigned hi = (unsigned)(skey[it] >> 32);
            if (((hi ^ prefix) & mask) == 0u)
                atomicAdd(&hist[(hi >> shift) & 255u], 1u);
        }
        __syncthreads();
        // suffix sum: scan[t] = sum_{e>=t} hist[e]
        scan[t] = hist[t];
        __syncthreads();
        #pragma unroll
        for (int off = 1; off < 256; off <<= 1) {
            unsigned v = (t + off < 256) ? scan[t + off] : 0u;
            __syncthreads();
            scan[t] += v;
            __syncthreads();
        }
        if (scan[t] >= kcur && (t == 255 || scan[t + 1] < kcur)) {
            sh_prefix = prefix | ((unsigned)t << shift);
            sh_mask   = mask | (0xFFu << shift);
            sh_k      = kcur - ((t == 255) ? 0u : scan[t + 1]);
        }
        __syncthreads();
    }
    const unsigned T32 = sh_prefix;  // high-32 bits of the rank-256 key

    // Compact all elements whose high-32 >= T32 (256 + high-bit ties).
    #pragma unroll
    for (int it = 0; it < 64; ++it) {
        unsigned long long key = skey[it];
        if ((unsigned)(key >> 32) >= T32) {
            unsigned pos = atomicAdd(&ccount, 1u);
            if (pos < 512u) {
                unsigned idx = (unsigned)(it * 256 + t);
                cand[pos] = make_ulonglong2(
                    key, (unsigned long long)(0xFFFFFFFFu - idx));
            }
        }
    }
    __syncthreads();
    const unsigned total = ccount < 512u ? ccount : 512u;
    for (int i = t; i < 512; i += 256)
        if ((unsigned)i >= total) cand[i] = make_ulonglong2(0ull, 0ull);

    // Bitonic sort 512 items ascending by (key, ~idx).
    for (int size = 2; size <= 512; size <<= 1) {
        for (int stride = size >> 1; stride > 0; stride >>= 1) {
            __syncthreads();
            int i  = ((t & ~(stride - 1)) << 1) | (t & (stride - 1));
            int jj = i + stride;
            bool up = ((i & size) == 0);
            ulonglong2 a = cand[i], c = cand[jj];
            bool agt = (a.x > c.x) || (a.x == c.x && a.y > c.y);
            if (agt == up) { cand[i] = c; cand[jj] = a; }
        }
    }
    __syncthreads();

    // t-th largest (desc key; equal keys -> larger ~idx first = lower idx).
    ulonglong2 v = cand[511 - t];
    unsigned idx = 0xFFFFFFFFu - (unsigned)v.y;
    unsigned long long ub = (v.x & 0x8000000000000000ull)
                          ? (v.x ^ 0x8000000000000000ull) : ~v.x;
    double sv = __longlong_as_double((long long)ub);

    ulonglong2 vm = cand[511];
    unsigned long long um = (vm.x & 0x8000000000000000ull)
                          ? (vm.x ^ 0x8000000000000000ull) : ~vm.x;
    double fm = __longlong_as_double((long long)um);

    double e = exp(sv - fm);
    double esum = e;
    #pragma unroll
    for (int m = 1; m < 64; m <<= 1) esum += __shfl_xor(esum, m);
    __shared__ double wsum[4];
    if ((t & 63) == 0) wsum[t >> 6] = esum;
    __syncthreads();
    const double tot = wsum[0] + wsum[1] + wsum[2] + wsum[3];

    out[b * KSEL + t]                = values[(size_t)b * LSEQ + idx]; // values_sel
    out[BATCH * KSEL + b * KSEL + t] = (float)(e / tot);               // weights
}

// ---------------------------------------------------------------------------
extern "C" void kernel_launch(void* const* d_in, const int* in_sizes, int n_in,
                              void* d_out, int out_size, void* d_ws, size_t ws_size,
                              hipStream_t stream)
{
    const float* q      = (const float*)d_in[0];  // (B,1,D)
    const float* keys   = (const float*)d_in[1];  // (B,L,D)
    const float* values = (const float*)d_in[2];  // (B,L,1)
    const float* g      = (const float*)d_in[3];  // scalar
    float* out   = (float*)d_out;                 // [B*K values_sel | B*K weights]
    double* sims = (double*)d_ws;                 // B*L doubles = 8 MB scratch

    sim_kernel<<<dim3(BATCH * (LSEQ / 256)), dim3(256), 0, stream>>>(q, keys, g, sims);
    topk_kernel<<<dim3(BATCH), dim3(256), 0, stream>>>(sims, values, out);
}